// Round 3
// baseline (17100.481 us; speedup 1.0000x reference)
//
#include <hip/hip_runtime.h>
#include <hip/hip_cooperative_groups.h>
#include <math.h>

namespace cg = cooperative_groups;

#define VV 32000
#define EE 256
#define HH 512
#define SS 400
#define TT 100
#define BB 32

// ---- workspace layout (float offsets) ----
#define WS_HPP   0u                       // 2 * 32*512 (h ping-pong)
#define WS_HALL  32768u                   // 100*32*512
#define WS_OE    (32768u + 1638400u)      // 3200*256
#define WS_M     (WS_OE + 819200u)        // 125*3200
#define WS_ZZ    (WS_M + 400000u)
#define WS_AM    (WS_ZZ + 400000u)
#define WS_GOLD  (WS_AM + 400000u)
#define WS_NLL   (WS_GOLD + 3200u)

__global__ __launch_bounds__(256) void k_zero(float* p, int n) {
    int i = blockIdx.x * 256 + threadIdx.x;
    if (i < n) p[i] = 0.f;
}

// ---- R1's exact GRU step body (bit-identical math), shared by the
// persistent kernel and the per-step fallback kernel. ----
__device__ __forceinline__ void gru_step_body(
    const float* __restrict__ emb, const int* __restrict__ tok, int sos,
    const float* __restrict__ Wih, const float* __restrict__ Whh,
    const float* __restrict__ bih, const float* __restrict__ bhh,
    const float* __restrict__ h_in, float* __restrict__ h_out,
    float (*z)[772], float (*part)[3][16][16],
    int tid, int cblk, int bg0)
{
    // stage x (gathered embedding) and h into LDS: 3072 float4 chunks / 768 thr
    #pragma unroll
    for (int i = 0; i < 4; ++i) {
        int idx = tid + i * 768;
        if (idx < 1024) {
            int bl = idx >> 6, k4 = idx & 63;
            int tk = sos ? 1 : tok[bg0 + bl];
            *(float4*)&z[bl][k4 * 4] = *(const float4*)(emb + (size_t)tk * EE + k4 * 4);
        } else {
            int j = idx - 1024;
            int bl = j >> 7, k4 = j & 127;
            *(float4*)&z[bl][256 + k4 * 4] = *(const float4*)(h_in + (bg0 + bl) * HH + k4 * 4);
        }
    }
    __syncthreads();

    const int b  = tid & 15;
    const int c  = (tid >> 4) & 15;
    const int kp = tid >> 8;                // 0..2
    const int cg = cblk * 16 + c;           // global h-col 0..511

    const float *w0, *w1, *w2; int koff;
    if (kp == 0) {
        w0 = Wih + (size_t)(0 * HH + cg) * EE;
        w1 = Wih + (size_t)(1 * HH + cg) * EE;
        w2 = Wih + (size_t)(2 * HH + cg) * EE;
        koff = 0;
    } else {
        int o = (kp == 1) ? 0 : 256;
        w0 = Whh + (size_t)(0 * HH + cg) * HH + o;
        w1 = Whh + (size_t)(1 * HH + cg) * HH + o;
        w2 = Whh + (size_t)(2 * HH + cg) * HH + o;
        koff = 256 + o;
    }

    float a0 = 0.f, a1 = 0.f, a2 = 0.f;
    #pragma unroll 8
    for (int k4 = 0; k4 < 64; ++k4) {
        float4 zv = *(const float4*)&z[b][koff + k4 * 4];
        float4 v0 = *(const float4*)(w0 + k4 * 4);
        float4 v1 = *(const float4*)(w1 + k4 * 4);
        float4 v2 = *(const float4*)(w2 + k4 * 4);
        a0 += zv.x * v0.x + zv.y * v0.y + zv.z * v0.z + zv.w * v0.w;
        a1 += zv.x * v1.x + zv.y * v1.y + zv.z * v1.z + zv.w * v1.w;
        a2 += zv.x * v2.x + zv.y * v2.y + zv.z * v2.z + zv.w * v2.w;
    }
    part[kp][0][c][b] = a0;
    part[kp][1][c][b] = a1;
    part[kp][2][c][b] = a2;
    __syncthreads();

    if (kp == 0) {
        float gr  = part[0][0][c][b] + part[1][0][c][b] + part[2][0][c][b];
        float gz  = part[0][1][c][b] + part[1][1][c][b] + part[2][1][c][b];
        float gin = part[0][2][c][b];
        float ghn = part[1][2][c][b] + part[2][2][c][b];
        float r  = 1.f / (1.f + expf(-(gr + bih[cg] + bhh[cg])));
        float zg = 1.f / (1.f + expf(-(gz + bih[HH + cg] + bhh[HH + cg])));
        float n  = tanhf(gin + bih[2 * HH + cg] + r * (ghn + bhh[2 * HH + cg]));
        float hp = z[b][256 + cg];
        h_out[(bg0 + b) * HH + cg] = (1.f - zg) * n + zg * hp;
    }
    // caller provides the inter-step barrier (grid.sync / kernel boundary)
}

// Fallback: one step per launch (R1-proven).
__global__ __launch_bounds__(768) void k_gru(
    const float* __restrict__ emb, const int* __restrict__ tok, int sos,
    const float* __restrict__ Wih, const float* __restrict__ Whh,
    const float* __restrict__ bih, const float* __restrict__ bhh,
    const float* __restrict__ h_in, float* __restrict__ h_out)
{
    __shared__ float z[16][772];
    __shared__ float part[3][3][16][16];
    gru_step_body(emb, tok, sos, Wih, Whh, bih, bhh, h_in, h_out,
                  z, part, threadIdx.x, blockIdx.x & 31, (blockIdx.x >> 5) * 16);
}

// Persistent: all 500 steps, one cooperative launch, R1 geometry (64 x 768).
__global__ __launch_bounds__(768) void k_rec(
    const float* __restrict__ emb, const int* __restrict__ src, const int* __restrict__ tgt,
    const float* __restrict__ eWih, const float* __restrict__ eWhh,
    const float* __restrict__ ebih, const float* __restrict__ ebhh,
    const float* __restrict__ dWih, const float* __restrict__ dWhh,
    const float* __restrict__ dbih, const float* __restrict__ dbhh,
    float* __restrict__ hpp, float* __restrict__ Hall)
{
    cg::grid_group grid = cg::this_grid();
    __shared__ float z[16][772];
    __shared__ float part[3][3][16][16];
    const int tid  = threadIdx.x;
    const int cblk = blockIdx.x & 31;
    const int bg0  = (blockIdx.x >> 5) * 16;

    for (int t = 0; t < SS; ++t) {
        const float* hin = hpp + (t & 1) * (BB * HH);
        float*       hout = hpp + ((t + 1) & 1) * (BB * HH);
        gru_step_body(emb, src + t * BB, 0, eWih, eWhh, ebih, ebhh,
                      hin, hout, z, part, tid, cblk, bg0);
        grid.sync();
    }
    // final encoder h is in hpp[0] (t=399 odd writes slot 0)
    for (int t = 0; t < TT; ++t) {
        const float* hin = t ? (Hall + (size_t)(t - 1) * (BB * HH)) : hpp;
        float*       hout = Hall + (size_t)t * (BB * HH);
        gru_step_body(emb, t ? (tgt + (t - 1) * BB) : src, (t == 0) ? 1 : 0,
                      dWih, dWhh, dbih, dbhh, hin, hout, z, part, tid, cblk, bg0);
        grid.sync();
    }
}

// OE[r][c] = dot(Hall[r][:512], preW[c][:512]) + preb[c].  grid (4, 200) x 256 thr.
__global__ __launch_bounds__(256) void k_outemb(
    const float* __restrict__ Hall, const float* __restrict__ preW,
    const float* __restrict__ preb, float* __restrict__ OE)
{
    __shared__ float hs[16][516];
    const int tid = threadIdx.x;
    const int c0 = blockIdx.x * 64;
    const int r0 = blockIdx.y * 16;
    #pragma unroll
    for (int i = 0; i < 8; ++i) {
        int idx = tid + i * 256;
        int rr = idx >> 7, k4 = idx & 127;
        *(float4*)&hs[rr][k4 * 4] = *(const float4*)(Hall + (size_t)(r0 + rr) * HH + k4 * 4);
    }
    __syncthreads();
    const int rr = tid & 15, cc = tid >> 4;
    int cj[4]; float acc[4];
    #pragma unroll
    for (int j = 0; j < 4; ++j) { cj[j] = c0 + cc + 16 * j; acc[j] = preb[cj[j]]; }
    for (int k4 = 0; k4 < 128; ++k4) {
        float4 hv = *(const float4*)&hs[rr][k4 * 4];
        #pragma unroll
        for (int j = 0; j < 4; ++j) {
            float4 wv = *(const float4*)(preW + (size_t)cj[j] * HH + k4 * 4);
            acc[j] += hv.x * wv.x + hv.y * wv.y + hv.z * wv.z + hv.w * wv.w;
        }
    }
    #pragma unroll
    for (int j = 0; j < 4; ++j) OE[(size_t)(r0 + rr) * EE + cj[j]] = acc[j];
}

// Fused tied-embedding logits + online-softmax slice partials.
__global__ __launch_bounds__(128) void k_logits(
    const float* __restrict__ OE, const float* __restrict__ emb,
    const float* __restrict__ outb, const int* __restrict__ tgt,
    float* __restrict__ m_arr, float* __restrict__ z_arr,
    unsigned int* __restrict__ am_arr, float* __restrict__ gold_arr)
{
    __shared__ float oes[32][260];
    __shared__ float ems[256][18];
    const int tid = threadIdx.x;
    const int c0 = blockIdx.x * 256;
    const int r0 = blockIdx.y * 32;

    #pragma unroll
    for (int i = 0; i < 16; ++i) {
        int idx = tid + i * 128;
        int rr2 = idx >> 6, k4 = idx & 63;
        *(float4*)&oes[rr2][k4 * 4] = *(const float4*)(OE + (size_t)(r0 + rr2) * EE + k4 * 4);
    }

    const int rr  = tid >> 5;
    const int ccg = tid & 31;
    float acc[8][8];
    #pragma unroll
    for (int i = 0; i < 8; ++i)
        #pragma unroll
        for (int j = 0; j < 8; ++j) acc[i][j] = 0.f;

    for (int kc = 0; kc < 16; ++kc) {
        __syncthreads();
        #pragma unroll
        for (int i = 0; i < 16; ++i) {
            int idx = tid + i * 128;
            int col = idx >> 3, f2 = idx & 7;
            *(float2*)&ems[col][f2 * 2] =
                *(const float2*)(emb + (size_t)(c0 + col) * EE + kc * 16 + f2 * 2);
        }
        __syncthreads();
        #pragma unroll
        for (int kk = 0; kk < 16; kk += 4) {
            float4 ov[8];
            #pragma unroll
            for (int i = 0; i < 8; ++i) ov[i] = *(const float4*)&oes[rr * 8 + i][kc * 16 + kk];
            #pragma unroll
            for (int j = 0; j < 8; ++j) {
                float2 e0 = *(const float2*)&ems[ccg + 32 * j][kk];
                float2 e1 = *(const float2*)&ems[ccg + 32 * j][kk + 2];
                #pragma unroll
                for (int i = 0; i < 8; ++i)
                    acc[i][j] += ov[i].x * e0.x + ov[i].y * e0.y + ov[i].z * e1.x + ov[i].w * e1.y;
            }
        }
    }

    #pragma unroll
    for (int i = 0; i < 8; ++i) {
        int r = r0 + rr * 8 + i;
        int gold = tgt[r];
        float vals[8]; float m = -3.4e38f; int cb = 0x7fffffff;
        #pragma unroll
        for (int j = 0; j < 8; ++j) {
            int cj = c0 + ccg + 32 * j;
            float v = acc[i][j] + outb[cj];
            vals[j] = v;
            if (v > m) { m = v; cb = cj; }
            if (cj == gold) gold_arr[r] = v;
        }
        for (int mk = 1; mk <= 16; mk <<= 1) {
            float mo = __shfl_xor(m, mk);
            int   co = __shfl_xor(cb, mk);
            if (mo > m || (mo == m && co < cb)) { m = mo; cb = co; }
        }
        float s = 0.f;
        #pragma unroll
        for (int j = 0; j < 8; ++j) s += expf(vals[j] - m);
        for (int mk = 1; mk <= 16; mk <<= 1) s += __shfl_xor(s, mk);
        if (ccg == 0) {
            size_t p = (size_t)blockIdx.x * 3200 + r;
            m_arr[p] = m; z_arr[p] = s; am_arr[p] = (unsigned)cb;
        }
    }
}

__global__ __launch_bounds__(256) void k_merge(
    const float* __restrict__ m_arr, const float* __restrict__ z_arr,
    const unsigned* __restrict__ am_arr, const float* __restrict__ gold_arr,
    float* __restrict__ nll, float* __restrict__ out)
{
    int r = blockIdx.x * 256 + threadIdx.x;
    if (r >= 3200) return;
    float M = -3.4e38f, Z = 0.f, bm = -3.4e38f; unsigned bc = 0u;
    for (int s = 0; s < 125; ++s) {
        size_t p = (size_t)s * 3200 + r;
        float ms = m_arr[p]; float zs = z_arr[p]; unsigned cs = am_arr[p];
        if (ms > M) { Z = Z * expf(M - ms) + zs; M = ms; }
        else        { Z += zs * expf(ms - M); }
        if (ms > bm || (ms == bm && cs < bc)) { bm = ms; bc = cs; }
    }
    float pg = expf(gold_arr[r] - M) / Z;
    nll[r] = -logf(pg + 1e-20f);
    out[r] = (float)bc;
}

__global__ __launch_bounds__(128) void k_loss(
    const float* __restrict__ nll, const int* __restrict__ tgt, float* __restrict__ out)
{
    __shared__ float ls[128];
    int t = threadIdx.x;
    float lt = 0.f;
    if (t < TT) {
        float s = 0.f; int cnt = 0;
        for (int b = 0; b < BB; ++b) {
            int g = tgt[t * BB + b];
            if (g != 0) { s += nll[t * BB + b]; cnt++; }
        }
        lt = s / fmaxf((float)cnt, 1.f);
    }
    ls[t] = lt;
    __syncthreads();
    for (int off = 64; off > 0; off >>= 1) {
        if (t < off) ls[t] += ls[t + off];
        __syncthreads();
    }
    if (t == 0) out[3200] = ls[0];
}

extern "C" void kernel_launch(void* const* d_in, const int* in_sizes, int n_in,
                              void* d_out, int out_size, void* d_ws, size_t ws_size,
                              hipStream_t stream) {
    const int*   src  = (const int*)  d_in[0];
    const int*   tgt  = (const int*)  d_in[1];
    const float* emb  = (const float*)d_in[2];
    const float* eWih = (const float*)d_in[3];
    const float* eWhh = (const float*)d_in[4];
    const float* ebih = (const float*)d_in[5];
    const float* ebhh = (const float*)d_in[6];
    const float* dWih = (const float*)d_in[7];
    const float* dWhh = (const float*)d_in[8];
    const float* dbih = (const float*)d_in[9];
    const float* dbhh = (const float*)d_in[10];
    const float* preW = (const float*)d_in[11];
    const float* preb = (const float*)d_in[12];
    const float* outb = (const float*)d_in[13];

    float* ws   = (float*)d_ws;
    float* out  = (float*)d_out;
    float* hpp  = ws + WS_HPP;
    float* Hall = ws + WS_HALL;
    float* OE   = ws + WS_OE;
    float* m_a  = ws + WS_M;
    float* z_a  = ws + WS_ZZ;
    unsigned* am_a = (unsigned*)(ws + WS_AM);
    float* gold = ws + WS_GOLD;
    float* nll  = ws + WS_NLL;

    // h0 = 0
    k_zero<<<64, 256, 0, stream>>>(hpp, BB * HH);

    // persistent cooperative recurrence; fall back to per-step launches on failure
    hipError_t coop_err;
    {
        const float* emb_ = emb; const int* src_ = src; const int* tgt_ = tgt;
        const float* a3 = eWih; const float* a4 = eWhh; const float* a5 = ebih; const float* a6 = ebhh;
        const float* a7 = dWih; const float* a8 = dWhh; const float* a9 = dbih; const float* a10 = dbhh;
        float* hpp_ = hpp; float* Hall_ = Hall;
        void* args[] = { (void*)&emb_, (void*)&src_, (void*)&tgt_,
                         (void*)&a3, (void*)&a4, (void*)&a5, (void*)&a6,
                         (void*)&a7, (void*)&a8, (void*)&a9, (void*)&a10,
                         (void*)&hpp_, (void*)&Hall_ };
        coop_err = hipLaunchCooperativeKernel((const void*)k_rec, dim3(64), dim3(768),
                                              args, 0, stream);
    }
    if (coop_err != hipSuccess) {
        // fallback: R1-proven 500-launch path
        for (int t = 0; t < SS; ++t) {
            const float* hin = hpp + (t & 1) * (BB * HH);
            float* hout      = hpp + ((t + 1) & 1) * (BB * HH);
            k_gru<<<64, 768, 0, stream>>>(emb, src + t * BB, 0,
                                          eWih, eWhh, ebih, ebhh, hin, hout);
        }
        for (int t = 0; t < TT; ++t) {
            const float* hin = (t == 0) ? hpp : (Hall + (size_t)(t - 1) * BB * HH);
            float* hout      = Hall + (size_t)t * BB * HH;
            const int* tp    = (t == 0) ? src : (tgt + (t - 1) * BB);
            k_gru<<<64, 768, 0, stream>>>(emb, tp, (t == 0) ? 1 : 0,
                                          dWih, dWhh, dbih, dbhh, hin, hout);
        }
    }

    // batched output path
    k_outemb<<<dim3(4, 200), 256, 0, stream>>>(Hall, preW, preb, OE);
    k_logits<<<dim3(125, 100), 128, 0, stream>>>(OE, emb, outb, tgt, m_a, z_a, am_a, gold);
    k_merge<<<13, 256, 0, stream>>>(m_a, z_a, am_a, gold, nll, out);
    k_loss<<<1, 128, 0, stream>>>(nll, tgt, out);
}

// Round 4
// 15583.574 us; speedup vs baseline: 1.0973x; 1.0973x over previous
//
#include <hip/hip_runtime.h>
#include <hip/hip_cooperative_groups.h>
#include <math.h>

namespace cg = cooperative_groups;

#define VV 32000
#define EE 256
#define HH 512
#define SS 400
#define TT 100
#define BB 32
#define NBLK 128

// ---- workspace layout (float offsets) ----
#define WS_HPP   0u                        // 2 * 32*512 (h ping-pong)
#define WS_ARR   32768u                    // 8192 int slots: per-step counters, stride 16
#define WS_HALL  40960u                    // 100*32*512
#define WS_OE    (40960u + 1638400u)       // 3200*256
#define WS_M     (WS_OE + 819200u)         // 125*3200
#define WS_ZZ    (WS_M + 400000u)
#define WS_AM    (WS_ZZ + 400000u)
#define WS_GOLD  (WS_AM + 400000u)
#define WS_NLL   (WS_GOLD + 3200u)

__global__ __launch_bounds__(256) void k_zero(float* p, int n) {
    int i = blockIdx.x * 256 + threadIdx.x;
    if (i < n) p[i] = 0.f;
}

// ==================== persistent recurrence (custom barrier) ====================
// 128 blocks x 256 threads, cooperative launch (co-residency), NO grid.sync().
// Block owns 4 h-cols x 3 gates; W_ih+W_hh slice LDS-resident per phase.
// Thread = (batch-quad bq, K-segment w): strided-K float4 (k4 = w + 32j).
// j=0,1 -> x part (W_ih cols), j=2..5 -> h part (W_hh cols).
__global__ __launch_bounds__(256, 1) void k_rec2(
    const float* __restrict__ emb, const int* __restrict__ src, const int* __restrict__ tgt,
    const float* __restrict__ eWih, const float* __restrict__ eWhh,
    const float* __restrict__ ebih, const float* __restrict__ ebhh,
    const float* __restrict__ dWih, const float* __restrict__ dWhh,
    const float* __restrict__ dbih, const float* __restrict__ dbhh,
    float* __restrict__ hpp, float* __restrict__ Hall, int* __restrict__ arr)
{
    __shared__ float4 Ws4[12 * 193];                  // 12 rows x 192 f4, pitch 193
    __shared__ __align__(16) float gact[8][4][4][4];  // [bq][q: r,z,nx,nh][c][i]
    const int tid = threadIdx.x;
    const int w   = tid & 31;                         // K-segment
    const int bq  = tid >> 5;                         // batch quad
    const int b0  = bq * 4;
    const int cg0 = blockIdx.x * 4;                   // block's first h-col

    int scount = 0;
    for (int phase = 0; phase < 2; ++phase) {
        const float* Wih = phase ? dWih : eWih;
        const float* Whh = phase ? dWhh : eWhh;
        const float* bih = phase ? dbih : ebih;
        const float* bhh = phase ? dbhh : ebhh;

        // stage weight slice into LDS (once per phase)
        for (int u = tid; u < 12 * 192; u += 256) {
            int r = u / 192, q = u - r * 192;
            int g = r >> 2, c = r & 3;
            size_t row = (size_t)(g * HH + cg0 + c);
            float4 v;
            if (q < 64) v = *(const float4*)(Wih + row * EE + q * 4);
            else        v = *(const float4*)(Whh + row * HH + (q - 64) * 4);
            Ws4[r * 193 + q] = v;
        }
        float br_ = 0.f, bz_ = 0.f, bnx_ = 0.f, bnh_ = 0.f;
        if (tid < 128) {
            int cg = cg0 + (tid & 3);
            br_  = bih[cg] + bhh[cg];
            bz_  = bih[HH + cg] + bhh[HH + cg];
            bnx_ = bih[2 * HH + cg];
            bnh_ = bhh[2 * HH + cg];
        }
        __syncthreads();

        const int T = phase ? TT : SS;
        for (int t = 0; t < T; ++t, ++scount) {
            const float* hprev; float* hnext;
            if (phase == 0) {
                hprev = hpp + (t & 1) * (BB * HH);
                hnext = hpp + ((t + 1) & 1) * (BB * HH);
            } else {
                hprev = t ? (Hall + (size_t)(t - 1) * (BB * HH)) : hpp;
                hnext = Hall + (size_t)t * (BB * HH);
            }

            // load this thread's x/h fragments: 4 batches x 6 float4
            float4 xh[4][6];
            #pragma unroll
            for (int i = 0; i < 4; ++i) {
                int tk = phase ? (t ? tgt[(t - 1) * BB + b0 + i] : 1) : src[t * BB + b0 + i];
                const float* xr = emb + (size_t)tk * EE + w * 4;
                xh[i][0] = *(const float4*)(xr);
                xh[i][1] = *(const float4*)(xr + 128);
                const float* hr = hprev + (b0 + i) * HH + w * 4;
                xh[i][2] = *(const float4*)(hr);
                xh[i][3] = *(const float4*)(hr + 128);
                xh[i][4] = *(const float4*)(hr + 256);
                xh[i][5] = *(const float4*)(hr + 384);
            }

            float aR[4][4], aZ[4][4], aNX[4][4], aNH[4][4];   // [c][i]
            #pragma unroll
            for (int c = 0; c < 4; ++c)
                #pragma unroll
                for (int i = 0; i < 4; ++i) { aR[c][i]=0.f; aZ[c][i]=0.f; aNX[c][i]=0.f; aNH[c][i]=0.f; }

            #pragma unroll
            for (int j = 0; j < 6; ++j) {
                #pragma unroll
                for (int g = 0; g < 3; ++g) {
                    #pragma unroll
                    for (int c = 0; c < 4; ++c) {
                        float4 wv = Ws4[(g * 4 + c) * 193 + w + 32 * j];
                        #pragma unroll
                        for (int i = 0; i < 4; ++i) {
                            float d = xh[i][j].x * wv.x + xh[i][j].y * wv.y
                                    + xh[i][j].z * wv.z + xh[i][j].w * wv.w;
                            if (g == 0)      aR[c][i]  += d;
                            else if (g == 1) aZ[c][i]  += d;
                            else if (j < 2)  aNX[c][i] += d;
                            else             aNH[c][i] += d;
                        }
                    }
                }
            }

            // butterfly-reduce over the 32 K-lanes (masks stay within 32-lane halves)
            #pragma unroll
            for (int m = 1; m <= 16; m <<= 1) {
                #pragma unroll
                for (int c = 0; c < 4; ++c)
                    #pragma unroll
                    for (int i = 0; i < 4; ++i) {
                        aR[c][i]  += __shfl_xor(aR[c][i],  m, 64);
                        aZ[c][i]  += __shfl_xor(aZ[c][i],  m, 64);
                        aNX[c][i] += __shfl_xor(aNX[c][i], m, 64);
                        aNH[c][i] += __shfl_xor(aNH[c][i], m, 64);
                    }
            }
            if (w == 0) {
                #pragma unroll
                for (int c = 0; c < 4; ++c) {
                    *(float4*)&gact[bq][0][c][0] = make_float4(aR[c][0],  aR[c][1],  aR[c][2],  aR[c][3]);
                    *(float4*)&gact[bq][1][c][0] = make_float4(aZ[c][0],  aZ[c][1],  aZ[c][2],  aZ[c][3]);
                    *(float4*)&gact[bq][2][c][0] = make_float4(aNX[c][0], aNX[c][1], aNX[c][2], aNX[c][3]);
                    *(float4*)&gact[bq][3][c][0] = make_float4(aNH[c][0], aNH[c][1], aNH[c][2], aNH[c][3]);
                }
            }
            __syncthreads();

            if (tid < 128) {
                int b = tid >> 2, c = tid & 3;
                int bq2 = b >> 2, i2 = b & 3;
                float gr  = gact[bq2][0][c][i2] + br_;
                float gz  = gact[bq2][1][c][i2] + bz_;
                float gnx = gact[bq2][2][c][i2] + bnx_;
                float gnh = gact[bq2][3][c][i2] + bnh_;
                float r = 1.f / (1.f + expf(-gr));
                float z = 1.f / (1.f + expf(-gz));
                float n = tanhf(gnx + r * gnh);
                float hp = hprev[b * HH + cg0 + c];
                hnext[b * HH + cg0 + c] = (1.f - z) * n + z * hp;
            }
            __threadfence();          // each thread's h stores drained to device scope
            __syncthreads();
            if (tid == 0) {
                int* ctr = arr + scount * 16;   // 64 B stride, pre-zeroed
                __hip_atomic_fetch_add(ctr, 1, __ATOMIC_RELEASE, __HIP_MEMORY_SCOPE_AGENT);
                while (__hip_atomic_load(ctr, __ATOMIC_ACQUIRE, __HIP_MEMORY_SCOPE_AGENT) < NBLK)
                    __builtin_amdgcn_s_sleep(1);
            }
            __syncthreads();
        }
    }
}

// ==================== R1-proven fallback (per-step launches) ====================
__device__ __forceinline__ void gru_step_body(
    const float* __restrict__ emb, const int* __restrict__ tok, int sos,
    const float* __restrict__ Wih, const float* __restrict__ Whh,
    const float* __restrict__ bih, const float* __restrict__ bhh,
    const float* __restrict__ h_in, float* __restrict__ h_out,
    float (*z)[772], float (*part)[3][16][16],
    int tid, int cblk, int bg0)
{
    #pragma unroll
    for (int i = 0; i < 4; ++i) {
        int idx = tid + i * 768;
        if (idx < 1024) {
            int bl = idx >> 6, k4 = idx & 63;
            int tk = sos ? 1 : tok[bg0 + bl];
            *(float4*)&z[bl][k4 * 4] = *(const float4*)(emb + (size_t)tk * EE + k4 * 4);
        } else {
            int j = idx - 1024;
            int bl = j >> 7, k4 = j & 127;
            *(float4*)&z[bl][256 + k4 * 4] = *(const float4*)(h_in + (bg0 + bl) * HH + k4 * 4);
        }
    }
    __syncthreads();
    const int b  = tid & 15;
    const int c  = (tid >> 4) & 15;
    const int kp = tid >> 8;
    const int cg = cblk * 16 + c;
    const float *w0, *w1, *w2; int koff;
    if (kp == 0) {
        w0 = Wih + (size_t)(0 * HH + cg) * EE;
        w1 = Wih + (size_t)(1 * HH + cg) * EE;
        w2 = Wih + (size_t)(2 * HH + cg) * EE;
        koff = 0;
    } else {
        int o = (kp == 1) ? 0 : 256;
        w0 = Whh + (size_t)(0 * HH + cg) * HH + o;
        w1 = Whh + (size_t)(1 * HH + cg) * HH + o;
        w2 = Whh + (size_t)(2 * HH + cg) * HH + o;
        koff = 256 + o;
    }
    float a0 = 0.f, a1 = 0.f, a2 = 0.f;
    #pragma unroll 8
    for (int k4 = 0; k4 < 64; ++k4) {
        float4 zv = *(const float4*)&z[b][koff + k4 * 4];
        float4 v0 = *(const float4*)(w0 + k4 * 4);
        float4 v1 = *(const float4*)(w1 + k4 * 4);
        float4 v2 = *(const float4*)(w2 + k4 * 4);
        a0 += zv.x * v0.x + zv.y * v0.y + zv.z * v0.z + zv.w * v0.w;
        a1 += zv.x * v1.x + zv.y * v1.y + zv.z * v1.z + zv.w * v1.w;
        a2 += zv.x * v2.x + zv.y * v2.y + zv.z * v2.z + zv.w * v2.w;
    }
    part[kp][0][c][b] = a0;
    part[kp][1][c][b] = a1;
    part[kp][2][c][b] = a2;
    __syncthreads();
    if (kp == 0) {
        float gr  = part[0][0][c][b] + part[1][0][c][b] + part[2][0][c][b];
        float gz  = part[0][1][c][b] + part[1][1][c][b] + part[2][1][c][b];
        float gin = part[0][2][c][b];
        float ghn = part[1][2][c][b] + part[2][2][c][b];
        float r  = 1.f / (1.f + expf(-(gr + bih[cg] + bhh[cg])));
        float zg = 1.f / (1.f + expf(-(gz + bih[HH + cg] + bhh[HH + cg])));
        float n  = tanhf(gin + bih[2 * HH + cg] + r * (ghn + bhh[2 * HH + cg]));
        float hp = z[b][256 + cg];
        h_out[(bg0 + b) * HH + cg] = (1.f - zg) * n + zg * hp;
    }
}

__global__ __launch_bounds__(768) void k_gru(
    const float* __restrict__ emb, const int* __restrict__ tok, int sos,
    const float* __restrict__ Wih, const float* __restrict__ Whh,
    const float* __restrict__ bih, const float* __restrict__ bhh,
    const float* __restrict__ h_in, float* __restrict__ h_out)
{
    __shared__ float z[16][772];
    __shared__ float part[3][3][16][16];
    gru_step_body(emb, tok, sos, Wih, Whh, bih, bhh, h_in, h_out,
                  z, part, threadIdx.x, blockIdx.x & 31, (blockIdx.x >> 5) * 16);
}

// ==================== output path (unchanged, R1-proven) ====================
__global__ __launch_bounds__(256) void k_outemb(
    const float* __restrict__ Hall, const float* __restrict__ preW,
    const float* __restrict__ preb, float* __restrict__ OE)
{
    __shared__ float hs[16][516];
    const int tid = threadIdx.x;
    const int c0 = blockIdx.x * 64;
    const int r0 = blockIdx.y * 16;
    #pragma unroll
    for (int i = 0; i < 8; ++i) {
        int idx = tid + i * 256;
        int rr = idx >> 7, k4 = idx & 127;
        *(float4*)&hs[rr][k4 * 4] = *(const float4*)(Hall + (size_t)(r0 + rr) * HH + k4 * 4);
    }
    __syncthreads();
    const int rr = tid & 15, cc = tid >> 4;
    int cj[4]; float acc[4];
    #pragma unroll
    for (int j = 0; j < 4; ++j) { cj[j] = c0 + cc + 16 * j; acc[j] = preb[cj[j]]; }
    for (int k4 = 0; k4 < 128; ++k4) {
        float4 hv = *(const float4*)&hs[rr][k4 * 4];
        #pragma unroll
        for (int j = 0; j < 4; ++j) {
            float4 wv = *(const float4*)(preW + (size_t)cj[j] * HH + k4 * 4);
            acc[j] += hv.x * wv.x + hv.y * wv.y + hv.z * wv.z + hv.w * wv.w;
        }
    }
    #pragma unroll
    for (int j = 0; j < 4; ++j) OE[(size_t)(r0 + rr) * EE + cj[j]] = acc[j];
}

__global__ __launch_bounds__(128) void k_logits(
    const float* __restrict__ OE, const float* __restrict__ emb,
    const float* __restrict__ outb, const int* __restrict__ tgt,
    float* __restrict__ m_arr, float* __restrict__ z_arr,
    unsigned int* __restrict__ am_arr, float* __restrict__ gold_arr)
{
    __shared__ float oes[32][260];
    __shared__ float ems[256][18];
    const int tid = threadIdx.x;
    const int c0 = blockIdx.x * 256;
    const int r0 = blockIdx.y * 32;

    #pragma unroll
    for (int i = 0; i < 16; ++i) {
        int idx = tid + i * 128;
        int rr2 = idx >> 6, k4 = idx & 63;
        *(float4*)&oes[rr2][k4 * 4] = *(const float4*)(OE + (size_t)(r0 + rr2) * EE + k4 * 4);
    }

    const int rr  = tid >> 5;
    const int ccg = tid & 31;
    float acc[8][8];
    #pragma unroll
    for (int i = 0; i < 8; ++i)
        #pragma unroll
        for (int j = 0; j < 8; ++j) acc[i][j] = 0.f;

    for (int kc = 0; kc < 16; ++kc) {
        __syncthreads();
        #pragma unroll
        for (int i = 0; i < 16; ++i) {
            int idx = tid + i * 128;
            int col = idx >> 3, f2 = idx & 7;
            *(float2*)&ems[col][f2 * 2] =
                *(const float2*)(emb + (size_t)(c0 + col) * EE + kc * 16 + f2 * 2);
        }
        __syncthreads();
        #pragma unroll
        for (int kk = 0; kk < 16; kk += 4) {
            float4 ov[8];
            #pragma unroll
            for (int i = 0; i < 8; ++i) ov[i] = *(const float4*)&oes[rr * 8 + i][kc * 16 + kk];
            #pragma unroll
            for (int j = 0; j < 8; ++j) {
                float2 e0 = *(const float2*)&ems[ccg + 32 * j][kk];
                float2 e1 = *(const float2*)&ems[ccg + 32 * j][kk + 2];
                #pragma unroll
                for (int i = 0; i < 8; ++i)
                    acc[i][j] += ov[i].x * e0.x + ov[i].y * e0.y + ov[i].z * e1.x + ov[i].w * e1.y;
            }
        }
    }

    #pragma unroll
    for (int i = 0; i < 8; ++i) {
        int r = r0 + rr * 8 + i;
        int gold = tgt[r];
        float vals[8]; float m = -3.4e38f; int cb = 0x7fffffff;
        #pragma unroll
        for (int j = 0; j < 8; ++j) {
            int cj = c0 + ccg + 32 * j;
            float v = acc[i][j] + outb[cj];
            vals[j] = v;
            if (v > m) { m = v; cb = cj; }
            if (cj == gold) gold_arr[r] = v;
        }
        for (int mk = 1; mk <= 16; mk <<= 1) {
            float mo = __shfl_xor(m, mk);
            int   co = __shfl_xor(cb, mk);
            if (mo > m || (mo == m && co < cb)) { m = mo; cb = co; }
        }
        float s = 0.f;
        #pragma unroll
        for (int j = 0; j < 8; ++j) s += expf(vals[j] - m);
        for (int mk = 1; mk <= 16; mk <<= 1) s += __shfl_xor(s, mk);
        if (ccg == 0) {
            size_t p = (size_t)blockIdx.x * 3200 + r;
            m_arr[p] = m; z_arr[p] = s; am_arr[p] = (unsigned)cb;
        }
    }
}

__global__ __launch_bounds__(256) void k_merge(
    const float* __restrict__ m_arr, const float* __restrict__ z_arr,
    const unsigned* __restrict__ am_arr, const float* __restrict__ gold_arr,
    float* __restrict__ nll, float* __restrict__ out)
{
    int r = blockIdx.x * 256 + threadIdx.x;
    if (r >= 3200) return;
    float M = -3.4e38f, Z = 0.f, bm = -3.4e38f; unsigned bc = 0u;
    for (int s = 0; s < 125; ++s) {
        size_t p = (size_t)s * 3200 + r;
        float ms = m_arr[p]; float zs = z_arr[p]; unsigned cs = am_arr[p];
        if (ms > M) { Z = Z * expf(M - ms) + zs; M = ms; }
        else        { Z += zs * expf(ms - M); }
        if (ms > bm || (ms == bm && cs < bc)) { bm = ms; bc = cs; }
    }
    float pg = expf(gold_arr[r] - M) / Z;
    nll[r] = -logf(pg + 1e-20f);
    out[r] = (float)bc;
}

__global__ __launch_bounds__(128) void k_loss(
    const float* __restrict__ nll, const int* __restrict__ tgt, float* __restrict__ out)
{
    __shared__ float ls[128];
    int t = threadIdx.x;
    float lt = 0.f;
    if (t < TT) {
        float s = 0.f; int cnt = 0;
        for (int b = 0; b < BB; ++b) {
            int g = tgt[t * BB + b];
            if (g != 0) { s += nll[t * BB + b]; cnt++; }
        }
        lt = s / fmaxf((float)cnt, 1.f);
    }
    ls[t] = lt;
    __syncthreads();
    for (int off = 64; off > 0; off >>= 1) {
        if (t < off) ls[t] += ls[t + off];
        __syncthreads();
    }
    if (t == 0) out[3200] = ls[0];
}

extern "C" void kernel_launch(void* const* d_in, const int* in_sizes, int n_in,
                              void* d_out, int out_size, void* d_ws, size_t ws_size,
                              hipStream_t stream) {
    const int*   src  = (const int*)  d_in[0];
    const int*   tgt  = (const int*)  d_in[1];
    const float* emb  = (const float*)d_in[2];
    const float* eWih = (const float*)d_in[3];
    const float* eWhh = (const float*)d_in[4];
    const float* ebih = (const float*)d_in[5];
    const float* ebhh = (const float*)d_in[6];
    const float* dWih = (const float*)d_in[7];
    const float* dWhh = (const float*)d_in[8];
    const float* dbih = (const float*)d_in[9];
    const float* dbhh = (const float*)d_in[10];
    const float* preW = (const float*)d_in[11];
    const float* preb = (const float*)d_in[12];
    const float* outb = (const float*)d_in[13];

    float* ws   = (float*)d_ws;
    float* out  = (float*)d_out;
    float* hpp  = ws + WS_HPP;
    int*   arr  = (int*)(ws + WS_ARR);
    float* Hall = ws + WS_HALL;
    float* OE   = ws + WS_OE;
    float* m_a  = ws + WS_M;
    float* z_a  = ws + WS_ZZ;
    unsigned* am_a = (unsigned*)(ws + WS_AM);
    float* gold = ws + WS_GOLD;
    float* nll  = ws + WS_NLL;

    // zero h0 AND the barrier counters (ws is re-poisoned before every call)
    k_zero<<<160, 256, 0, stream>>>(ws, 40960);

    hipError_t coop_err;
    {
        const float* emb_ = emb; const int* src_ = src; const int* tgt_ = tgt;
        const float* a3 = eWih; const float* a4 = eWhh; const float* a5 = ebih; const float* a6 = ebhh;
        const float* a7 = dWih; const float* a8 = dWhh; const float* a9 = dbih; const float* a10 = dbhh;
        float* hpp_ = hpp; float* Hall_ = Hall; int* arr_ = arr;
        void* args[] = { (void*)&emb_, (void*)&src_, (void*)&tgt_,
                         (void*)&a3, (void*)&a4, (void*)&a5, (void*)&a6,
                         (void*)&a7, (void*)&a8, (void*)&a9, (void*)&a10,
                         (void*)&hpp_, (void*)&Hall_, (void*)&arr_ };
        coop_err = hipLaunchCooperativeKernel((const void*)k_rec2, dim3(NBLK), dim3(256),
                                              args, 0, stream);
    }
    if (coop_err != hipSuccess) {
        for (int t = 0; t < SS; ++t) {
            const float* hin = hpp + (t & 1) * (BB * HH);
            float* hout      = hpp + ((t + 1) & 1) * (BB * HH);
            k_gru<<<64, 768, 0, stream>>>(emb, src + t * BB, 0,
                                          eWih, eWhh, ebih, ebhh, hin, hout);
        }
        for (int t = 0; t < TT; ++t) {
            const float* hin = (t == 0) ? hpp : (Hall + (size_t)(t - 1) * BB * HH);
            float* hout      = Hall + (size_t)t * BB * HH;
            const int* tp    = (t == 0) ? src : (tgt + (t - 1) * BB);
            k_gru<<<64, 768, 0, stream>>>(emb, tp, (t == 0) ? 1 : 0,
                                          dWih, dWhh, dbih, dbhh, hin, hout);
        }
    }

    k_outemb<<<dim3(4, 200), 256, 0, stream>>>(Hall, preW, preb, OE);
    k_logits<<<dim3(125, 100), 128, 0, stream>>>(OE, emb, outb, tgt, m_a, z_a, am_a, gold);
    k_merge<<<13, 256, 0, stream>>>(m_a, z_a, am_a, gold, nll, out);
    k_loss<<<1, 128, 0, stream>>>(nll, tgt, out);
}

// Round 5
// 10030.570 us; speedup vs baseline: 1.7048x; 1.5536x over previous
//
#include <hip/hip_runtime.h>
#include <hip/hip_cooperative_groups.h>
#include <math.h>

namespace cg = cooperative_groups;

#define VV 32000
#define EE 256
#define HH 512
#define SS 400
#define TT 100
#define BB 32
#define NBLK 128

// ---- workspace layout (float offsets) ----
#define WS_HPP   0u                        // 2 * 32*512 (h ping-pong)
#define WS_ARR   32768u                    // 8192 int slots: per-step counters, stride 16
#define WS_HALL  40960u                    // 100*32*512
#define WS_OE    (40960u + 1638400u)       // 3200*256
#define WS_M     (WS_OE + 819200u)         // 125*3200
#define WS_ZZ    (WS_M + 400000u)
#define WS_AM    (WS_ZZ + 400000u)
#define WS_GOLD  (WS_AM + 400000u)
#define WS_NLL   (WS_GOLD + 3200u)

__global__ __launch_bounds__(256) void k_zero(float* p, int n) {
    int i = blockIdx.x * 256 + threadIdx.x;
    if (i < n) p[i] = 0.f;
}

// Coherent (MALL-level) float4 load: 4 relaxed agent-scope atomic loads.
// sc0/sc1 loads bypass the non-coherent per-XCD L2 and read the Infinity
// Cache directly -> no buffer_inv needed, fresh data across XCDs.
__device__ __forceinline__ float4 ld4_coh(const float* p) {
    float4 v;
    v.x = __hip_atomic_load(p + 0, __ATOMIC_RELAXED, __HIP_MEMORY_SCOPE_AGENT);
    v.y = __hip_atomic_load(p + 1, __ATOMIC_RELAXED, __HIP_MEMORY_SCOPE_AGENT);
    v.z = __hip_atomic_load(p + 2, __ATOMIC_RELAXED, __HIP_MEMORY_SCOPE_AGENT);
    v.w = __hip_atomic_load(p + 3, __ATOMIC_RELAXED, __HIP_MEMORY_SCOPE_AGENT);
    return v;
}

// ==================== persistent recurrence (MALL-coherent barrier) ====================
// 128 blocks x 256 threads, cooperative launch. Block owns 4 h-cols x 3 gates;
// W_ih+W_hh slice LDS-resident per phase. Thread = (batch-quad bq, K-seg w).
// ALL cross-block h traffic via relaxed agent-scope atomics (sc0 sc1 -> MALL);
// barrier = relaxed fetch_add + relaxed poll. NO buffer_wbl2 / buffer_inv.
__global__ __launch_bounds__(256, 1) void k_rec2(
    const float* __restrict__ emb, const int* __restrict__ src, const int* __restrict__ tgt,
    const float* __restrict__ eWih, const float* __restrict__ eWhh,
    const float* __restrict__ ebih, const float* __restrict__ ebhh,
    const float* __restrict__ dWih, const float* __restrict__ dWhh,
    const float* __restrict__ dbih, const float* __restrict__ dbhh,
    float* __restrict__ hpp, float* __restrict__ Hall, int* __restrict__ arr)
{
    __shared__ float4 Ws4[12 * 193];                  // 12 rows x 192 f4, pitch 193
    __shared__ __align__(16) float gact[8][4][4][4];  // [bq][q: r,z,nx,nh][c][i]
    const int tid = threadIdx.x;
    const int w   = tid & 31;                         // K-segment
    const int bq  = tid >> 5;                         // batch quad
    const int b0  = bq * 4;
    const int cg0 = blockIdx.x * 4;                   // block's first h-col

    int scount = 0;
    for (int phase = 0; phase < 2; ++phase) {
        const float* Wih = phase ? dWih : eWih;
        const float* Whh = phase ? dWhh : eWhh;
        const float* bih = phase ? dbih : ebih;
        const float* bhh = phase ? dbhh : ebhh;

        // stage weight slice into LDS (once per phase)
        for (int u = tid; u < 12 * 192; u += 256) {
            int r = u / 192, q = u - r * 192;
            int g = r >> 2, c = r & 3;
            size_t row = (size_t)(g * HH + cg0 + c);
            float4 v;
            if (q < 64) v = *(const float4*)(Wih + row * EE + q * 4);
            else        v = *(const float4*)(Whh + row * HH + (q - 64) * 4);
            Ws4[r * 193 + q] = v;
        }
        float br_ = 0.f, bz_ = 0.f, bnx_ = 0.f, bnh_ = 0.f;
        if (tid < 128) {
            int cg = cg0 + (tid & 3);
            br_  = bih[cg] + bhh[cg];
            bz_  = bih[HH + cg] + bhh[HH + cg];
            bnx_ = bih[2 * HH + cg];
            bnh_ = bhh[2 * HH + cg];
        }
        __syncthreads();

        const int T = phase ? TT : SS;
        for (int t = 0; t < T; ++t, ++scount) {
            const float* hprev; float* hnext;
            if (phase == 0) {
                hprev = hpp + (t & 1) * (BB * HH);
                hnext = hpp + ((t + 1) & 1) * (BB * HH);
            } else {
                hprev = t ? (Hall + (size_t)(t - 1) * (BB * HH)) : hpp;
                hnext = Hall + (size_t)t * (BB * HH);
            }

            // load this thread's x/h fragments: 4 batches x 6 float4.
            // x from emb: normal cached loads (read-only). h: coherent sc loads.
            float4 xh[4][6];
            #pragma unroll
            for (int i = 0; i < 4; ++i) {
                int tk = phase ? (t ? tgt[(t - 1) * BB + b0 + i] : 1) : src[t * BB + b0 + i];
                const float* xr = emb + (size_t)tk * EE + w * 4;
                xh[i][0] = *(const float4*)(xr);
                xh[i][1] = *(const float4*)(xr + 128);
                const float* hr = hprev + (b0 + i) * HH + w * 4;
                xh[i][2] = ld4_coh(hr);
                xh[i][3] = ld4_coh(hr + 128);
                xh[i][4] = ld4_coh(hr + 256);
                xh[i][5] = ld4_coh(hr + 384);
            }

            float aR[4][4], aZ[4][4], aNX[4][4], aNH[4][4];   // [c][i]
            #pragma unroll
            for (int c = 0; c < 4; ++c)
                #pragma unroll
                for (int i = 0; i < 4; ++i) { aR[c][i]=0.f; aZ[c][i]=0.f; aNX[c][i]=0.f; aNH[c][i]=0.f; }

            #pragma unroll
            for (int j = 0; j < 6; ++j) {
                #pragma unroll
                for (int g = 0; g < 3; ++g) {
                    #pragma unroll
                    for (int c = 0; c < 4; ++c) {
                        float4 wv = Ws4[(g * 4 + c) * 193 + w + 32 * j];
                        #pragma unroll
                        for (int i = 0; i < 4; ++i) {
                            float d = xh[i][j].x * wv.x + xh[i][j].y * wv.y
                                    + xh[i][j].z * wv.z + xh[i][j].w * wv.w;
                            if (g == 0)      aR[c][i]  += d;
                            else if (g == 1) aZ[c][i]  += d;
                            else if (j < 2)  aNX[c][i] += d;
                            else             aNH[c][i] += d;
                        }
                    }
                }
            }

            // butterfly-reduce over the 32 K-lanes
            #pragma unroll
            for (int m = 1; m <= 16; m <<= 1) {
                #pragma unroll
                for (int c = 0; c < 4; ++c)
                    #pragma unroll
                    for (int i = 0; i < 4; ++i) {
                        aR[c][i]  += __shfl_xor(aR[c][i],  m, 64);
                        aZ[c][i]  += __shfl_xor(aZ[c][i],  m, 64);
                        aNX[c][i] += __shfl_xor(aNX[c][i], m, 64);
                        aNH[c][i] += __shfl_xor(aNH[c][i], m, 64);
                    }
            }
            if (w == 0) {
                #pragma unroll
                for (int c = 0; c < 4; ++c) {
                    *(float4*)&gact[bq][0][c][0] = make_float4(aR[c][0],  aR[c][1],  aR[c][2],  aR[c][3]);
                    *(float4*)&gact[bq][1][c][0] = make_float4(aZ[c][0],  aZ[c][1],  aZ[c][2],  aZ[c][3]);
                    *(float4*)&gact[bq][2][c][0] = make_float4(aNX[c][0], aNX[c][1], aNX[c][2], aNX[c][3]);
                    *(float4*)&gact[bq][3][c][0] = make_float4(aNH[c][0], aNH[c][1], aNH[c][2], aNH[c][3]);
                }
            }
            __syncthreads();

            if (tid < 128) {
                int b = tid >> 2, c = tid & 3;
                int bq2 = b >> 2, i2 = b & 3;
                float gr  = gact[bq2][0][c][i2] + br_;
                float gz  = gact[bq2][1][c][i2] + bz_;
                float gnx = gact[bq2][2][c][i2] + bnx_;
                float gnh = gact[bq2][3][c][i2] + bnh_;
                float r = 1.f / (1.f + expf(-gr));
                float z = 1.f / (1.f + expf(-gz));
                float n = tanhf(gnx + r * gnh);
                float hp = __hip_atomic_load(hprev + b * HH + cg0 + c,
                                             __ATOMIC_RELAXED, __HIP_MEMORY_SCOPE_AGENT);
                __hip_atomic_store(hnext + b * HH + cg0 + c, (1.f - z) * n + z * hp,
                                   __ATOMIC_RELAXED, __HIP_MEMORY_SCOPE_AGENT);
            }
            // drain this wave's coherent stores to the MALL, then block-barrier:
            // after it, ALL waves' h stores are at the coherence point.
            __builtin_amdgcn_s_waitcnt(0);
            __syncthreads();
            if (tid == 0) {
                int* ctr = arr + scount * 16;   // 64 B stride, pre-zeroed
                __hip_atomic_fetch_add(ctr, 1, __ATOMIC_RELAXED, __HIP_MEMORY_SCOPE_AGENT);
                while (__hip_atomic_load(ctr, __ATOMIC_RELAXED, __HIP_MEMORY_SCOPE_AGENT) < NBLK)
                    __builtin_amdgcn_s_sleep(2);
            }
            __syncthreads();
        }
    }
}

// ==================== R1-proven fallback (per-step launches) ====================
__device__ __forceinline__ void gru_step_body(
    const float* __restrict__ emb, const int* __restrict__ tok, int sos,
    const float* __restrict__ Wih, const float* __restrict__ Whh,
    const float* __restrict__ bih, const float* __restrict__ bhh,
    const float* __restrict__ h_in, float* __restrict__ h_out,
    float (*z)[772], float (*part)[3][16][16],
    int tid, int cblk, int bg0)
{
    #pragma unroll
    for (int i = 0; i < 4; ++i) {
        int idx = tid + i * 768;
        if (idx < 1024) {
            int bl = idx >> 6, k4 = idx & 63;
            int tk = sos ? 1 : tok[bg0 + bl];
            *(float4*)&z[bl][k4 * 4] = *(const float4*)(emb + (size_t)tk * EE + k4 * 4);
        } else {
            int j = idx - 1024;
            int bl = j >> 7, k4 = j & 127;
            *(float4*)&z[bl][256 + k4 * 4] = *(const float4*)(h_in + (bg0 + bl) * HH + k4 * 4);
        }
    }
    __syncthreads();
    const int b  = tid & 15;
    const int c  = (tid >> 4) & 15;
    const int kp = tid >> 8;
    const int cg = cblk * 16 + c;
    const float *w0, *w1, *w2; int koff;
    if (kp == 0) {
        w0 = Wih + (size_t)(0 * HH + cg) * EE;
        w1 = Wih + (size_t)(1 * HH + cg) * EE;
        w2 = Wih + (size_t)(2 * HH + cg) * EE;
        koff = 0;
    } else {
        int o = (kp == 1) ? 0 : 256;
        w0 = Whh + (size_t)(0 * HH + cg) * HH + o;
        w1 = Whh + (size_t)(1 * HH + cg) * HH + o;
        w2 = Whh + (size_t)(2 * HH + cg) * HH + o;
        koff = 256 + o;
    }
    float a0 = 0.f, a1 = 0.f, a2 = 0.f;
    #pragma unroll 8
    for (int k4 = 0; k4 < 64; ++k4) {
        float4 zv = *(const float4*)&z[b][koff + k4 * 4];
        float4 v0 = *(const float4*)(w0 + k4 * 4);
        float4 v1 = *(const float4*)(w1 + k4 * 4);
        float4 v2 = *(const float4*)(w2 + k4 * 4);
        a0 += zv.x * v0.x + zv.y * v0.y + zv.z * v0.z + zv.w * v0.w;
        a1 += zv.x * v1.x + zv.y * v1.y + zv.z * v1.z + zv.w * v1.w;
        a2 += zv.x * v2.x + zv.y * v2.y + zv.z * v2.z + zv.w * v2.w;
    }
    part[kp][0][c][b] = a0;
    part[kp][1][c][b] = a1;
    part[kp][2][c][b] = a2;
    __syncthreads();
    if (kp == 0) {
        float gr  = part[0][0][c][b] + part[1][0][c][b] + part[2][0][c][b];
        float gz  = part[0][1][c][b] + part[1][1][c][b] + part[2][1][c][b];
        float gin = part[0][2][c][b];
        float ghn = part[1][2][c][b] + part[2][2][c][b];
        float r  = 1.f / (1.f + expf(-(gr + bih[cg] + bhh[cg])));
        float zg = 1.f / (1.f + expf(-(gz + bih[HH + cg] + bhh[HH + cg])));
        float n  = tanhf(gin + bih[2 * HH + cg] + r * (ghn + bhh[2 * HH + cg]));
        float hp = z[b][256 + cg];
        h_out[(bg0 + b) * HH + cg] = (1.f - zg) * n + zg * hp;
    }
}

__global__ __launch_bounds__(768) void k_gru(
    const float* __restrict__ emb, const int* __restrict__ tok, int sos,
    const float* __restrict__ Wih, const float* __restrict__ Whh,
    const float* __restrict__ bih, const float* __restrict__ bhh,
    const float* __restrict__ h_in, float* __restrict__ h_out)
{
    __shared__ float z[16][772];
    __shared__ float part[3][3][16][16];
    gru_step_body(emb, tok, sos, Wih, Whh, bih, bhh, h_in, h_out,
                  z, part, threadIdx.x, blockIdx.x & 31, (blockIdx.x >> 5) * 16);
}

// ==================== output path (unchanged, R1-proven) ====================
__global__ __launch_bounds__(256) void k_outemb(
    const float* __restrict__ Hall, const float* __restrict__ preW,
    const float* __restrict__ preb, float* __restrict__ OE)
{
    __shared__ float hs[16][516];
    const int tid = threadIdx.x;
    const int c0 = blockIdx.x * 64;
    const int r0 = blockIdx.y * 16;
    #pragma unroll
    for (int i = 0; i < 8; ++i) {
        int idx = tid + i * 256;
        int rr = idx >> 7, k4 = idx & 127;
        *(float4*)&hs[rr][k4 * 4] = *(const float4*)(Hall + (size_t)(r0 + rr) * HH + k4 * 4);
    }
    __syncthreads();
    const int rr = tid & 15, cc = tid >> 4;
    int cj[4]; float acc[4];
    #pragma unroll
    for (int j = 0; j < 4; ++j) { cj[j] = c0 + cc + 16 * j; acc[j] = preb[cj[j]]; }
    for (int k4 = 0; k4 < 128; ++k4) {
        float4 hv = *(const float4*)&hs[rr][k4 * 4];
        #pragma unroll
        for (int j = 0; j < 4; ++j) {
            float4 wv = *(const float4*)(preW + (size_t)cj[j] * HH + k4 * 4);
            acc[j] += hv.x * wv.x + hv.y * wv.y + hv.z * wv.z + hv.w * wv.w;
        }
    }
    #pragma unroll
    for (int j = 0; j < 4; ++j) OE[(size_t)(r0 + rr) * EE + cj[j]] = acc[j];
}

__global__ __launch_bounds__(128) void k_logits(
    const float* __restrict__ OE, const float* __restrict__ emb,
    const float* __restrict__ outb, const int* __restrict__ tgt,
    float* __restrict__ m_arr, float* __restrict__ z_arr,
    unsigned int* __restrict__ am_arr, float* __restrict__ gold_arr)
{
    __shared__ float oes[32][260];
    __shared__ float ems[256][18];
    const int tid = threadIdx.x;
    const int c0 = blockIdx.x * 256;
    const int r0 = blockIdx.y * 32;

    #pragma unroll
    for (int i = 0; i < 16; ++i) {
        int idx = tid + i * 128;
        int rr2 = idx >> 6, k4 = idx & 63;
        *(float4*)&oes[rr2][k4 * 4] = *(const float4*)(OE + (size_t)(r0 + rr2) * EE + k4 * 4);
    }

    const int rr  = tid >> 5;
    const int ccg = tid & 31;
    float acc[8][8];
    #pragma unroll
    for (int i = 0; i < 8; ++i)
        #pragma unroll
        for (int j = 0; j < 8; ++j) acc[i][j] = 0.f;

    for (int kc = 0; kc < 16; ++kc) {
        __syncthreads();
        #pragma unroll
        for (int i = 0; i < 16; ++i) {
            int idx = tid + i * 128;
            int col = idx >> 3, f2 = idx & 7;
            *(float2*)&ems[col][f2 * 2] =
                *(const float2*)(emb + (size_t)(c0 + col) * EE + kc * 16 + f2 * 2);
        }
        __syncthreads();
        #pragma unroll
        for (int kk = 0; kk < 16; kk += 4) {
            float4 ov[8];
            #pragma unroll
            for (int i = 0; i < 8; ++i) ov[i] = *(const float4*)&oes[rr * 8 + i][kc * 16 + kk];
            #pragma unroll
            for (int j = 0; j < 8; ++j) {
                float2 e0 = *(const float2*)&ems[ccg + 32 * j][kk];
                float2 e1 = *(const float2*)&ems[ccg + 32 * j][kk + 2];
                #pragma unroll
                for (int i = 0; i < 8; ++i)
                    acc[i][j] += ov[i].x * e0.x + ov[i].y * e0.y + ov[i].z * e1.x + ov[i].w * e1.y;
            }
        }
    }

    #pragma unroll
    for (int i = 0; i < 8; ++i) {
        int r = r0 + rr * 8 + i;
        int gold = tgt[r];
        float vals[8]; float m = -3.4e38f; int cb = 0x7fffffff;
        #pragma unroll
        for (int j = 0; j < 8; ++j) {
            int cj = c0 + ccg + 32 * j;
            float v = acc[i][j] + outb[cj];
            vals[j] = v;
            if (v > m) { m = v; cb = cj; }
            if (cj == gold) gold_arr[r] = v;
        }
        for (int mk = 1; mk <= 16; mk <<= 1) {
            float mo = __shfl_xor(m, mk);
            int   co = __shfl_xor(cb, mk);
            if (mo > m || (mo == m && co < cb)) { m = mo; cb = co; }
        }
        float s = 0.f;
        #pragma unroll
        for (int j = 0; j < 8; ++j) s += expf(vals[j] - m);
        for (int mk = 1; mk <= 16; mk <<= 1) s += __shfl_xor(s, mk);
        if (ccg == 0) {
            size_t p = (size_t)blockIdx.x * 3200 + r;
            m_arr[p] = m; z_arr[p] = s; am_arr[p] = (unsigned)cb;
        }
    }
}

__global__ __launch_bounds__(256) void k_merge(
    const float* __restrict__ m_arr, const float* __restrict__ z_arr,
    const unsigned* __restrict__ am_arr, const float* __restrict__ gold_arr,
    float* __restrict__ nll, float* __restrict__ out)
{
    int r = blockIdx.x * 256 + threadIdx.x;
    if (r >= 3200) return;
    float M = -3.4e38f, Z = 0.f, bm = -3.4e38f; unsigned bc = 0u;
    for (int s = 0; s < 125; ++s) {
        size_t p = (size_t)s * 3200 + r;
        float ms = m_arr[p]; float zs = z_arr[p]; unsigned cs = am_arr[p];
        if (ms > M) { Z = Z * expf(M - ms) + zs; M = ms; }
        else        { Z += zs * expf(ms - M); }
        if (ms > bm || (ms == bm && cs < bc)) { bm = ms; bc = cs; }
    }
    float pg = expf(gold_arr[r] - M) / Z;
    nll[r] = -logf(pg + 1e-20f);
    out[r] = (float)bc;
}

__global__ __launch_bounds__(128) void k_loss(
    const float* __restrict__ nll, const int* __restrict__ tgt, float* __restrict__ out)
{
    __shared__ float ls[128];
    int t = threadIdx.x;
    float lt = 0.f;
    if (t < TT) {
        float s = 0.f; int cnt = 0;
        for (int b = 0; b < BB; ++b) {
            int g = tgt[t * BB + b];
            if (g != 0) { s += nll[t * BB + b]; cnt++; }
        }
        lt = s / fmaxf((float)cnt, 1.f);
    }
    ls[t] = lt;
    __syncthreads();
    for (int off = 64; off > 0; off >>= 1) {
        if (t < off) ls[t] += ls[t + off];
        __syncthreads();
    }
    if (t == 0) out[3200] = ls[0];
}

extern "C" void kernel_launch(void* const* d_in, const int* in_sizes, int n_in,
                              void* d_out, int out_size, void* d_ws, size_t ws_size,
                              hipStream_t stream) {
    const int*   src  = (const int*)  d_in[0];
    const int*   tgt  = (const int*)  d_in[1];
    const float* emb  = (const float*)d_in[2];
    const float* eWih = (const float*)d_in[3];
    const float* eWhh = (const float*)d_in[4];
    const float* ebih = (const float*)d_in[5];
    const float* ebhh = (const float*)d_in[6];
    const float* dWih = (const float*)d_in[7];
    const float* dWhh = (const float*)d_in[8];
    const float* dbih = (const float*)d_in[9];
    const float* dbhh = (const float*)d_in[10];
    const float* preW = (const float*)d_in[11];
    const float* preb = (const float*)d_in[12];
    const float* outb = (const float*)d_in[13];

    float* ws   = (float*)d_ws;
    float* out  = (float*)d_out;
    float* hpp  = ws + WS_HPP;
    int*   arr  = (int*)(ws + WS_ARR);
    float* Hall = ws + WS_HALL;
    float* OE   = ws + WS_OE;
    float* m_a  = ws + WS_M;
    float* z_a  = ws + WS_ZZ;
    unsigned* am_a = (unsigned*)(ws + WS_AM);
    float* gold = ws + WS_GOLD;
    float* nll  = ws + WS_NLL;

    // zero h0 AND the barrier counters (ws is re-poisoned before every call)
    k_zero<<<160, 256, 0, stream>>>(ws, 40960);

    hipError_t coop_err;
    {
        const float* emb_ = emb; const int* src_ = src; const int* tgt_ = tgt;
        const float* a3 = eWih; const float* a4 = eWhh; const float* a5 = ebih; const float* a6 = ebhh;
        const float* a7 = dWih; const float* a8 = dWhh; const float* a9 = dbih; const float* a10 = dbhh;
        float* hpp_ = hpp; float* Hall_ = Hall; int* arr_ = arr;
        void* args[] = { (void*)&emb_, (void*)&src_, (void*)&tgt_,
                         (void*)&a3, (void*)&a4, (void*)&a5, (void*)&a6,
                         (void*)&a7, (void*)&a8, (void*)&a9, (void*)&a10,
                         (void*)&hpp_, (void*)&Hall_, (void*)&arr_ };
        coop_err = hipLaunchCooperativeKernel((const void*)k_rec2, dim3(NBLK), dim3(256),
                                              args, 0, stream);
    }
    if (coop_err != hipSuccess) {
        for (int t = 0; t < SS; ++t) {
            const float* hin = hpp + (t & 1) * (BB * HH);
            float* hout      = hpp + ((t + 1) & 1) * (BB * HH);
            k_gru<<<64, 768, 0, stream>>>(emb, src + t * BB, 0,
                                          eWih, eWhh, ebih, ebhh, hin, hout);
        }
        for (int t = 0; t < TT; ++t) {
            const float* hin = (t == 0) ? hpp : (Hall + (size_t)(t - 1) * BB * HH);
            float* hout      = Hall + (size_t)t * BB * HH;
            const int* tp    = (t == 0) ? src : (tgt + (t - 1) * BB);
            k_gru<<<64, 768, 0, stream>>>(emb, tp, (t == 0) ? 1 : 0,
                                          dWih, dWhh, dbih, dbhh, hin, hout);
        }
    }

    k_outemb<<<dim3(4, 200), 256, 0, stream>>>(Hall, preW, preb, OE);
    k_logits<<<dim3(125, 100), 128, 0, stream>>>(OE, emb, outb, tgt, m_a, z_a, am_a, gold);
    k_merge<<<13, 256, 0, stream>>>(m_a, z_a, am_a, gold, nll, out);
    k_loss<<<1, 128, 0, stream>>>(nll, tgt, out);
}

// Round 6
// 9264.449 us; speedup vs baseline: 1.8458x; 1.0827x over previous
//
#include <hip/hip_runtime.h>
#include <hip/hip_cooperative_groups.h>
#include <math.h>

#define VV 32000
#define EE 256
#define HH 512
#define SS 400
#define TT 100
#define BB 32
#define NBLK 128

// ---- workspace layout (float offsets) ----
#define WS_HPP   0u                        // 2 * 32*512 (h ping-pong)
#define WS_ARR   32768u                    // 256000 ints: 500 steps x 8 lines x 64-int stride
#define WS_HALL  288768u                   // 100*32*512
#define WS_OE    (288768u + 1638400u)      // 3200*256
#define WS_M     (WS_OE + 819200u)         // 125*3200
#define WS_ZZ    (WS_M + 400000u)
#define WS_AM    (WS_ZZ + 400000u)
#define WS_GOLD  (WS_AM + 400000u)
#define WS_NLL   (WS_GOLD + 3200u)

__global__ __launch_bounds__(256) void k_zero(float* p, int n) {
    int i = blockIdx.x * 256 + threadIdx.x;
    if (i < n) p[i] = 0.f;
}

__device__ __forceinline__ float dot4(float4 a, float4 b) {
    return a.x * b.x + a.y * b.y + a.z * b.z + a.w * b.w;
}

// Coherent (MALL-level) float4 load: relaxed agent-scope atomic loads bypass
// the non-coherent per-XCD L2 (no buffer_inv needed).
__device__ __forceinline__ float4 ld4_coh(const float* p) {
    float4 v;
    v.x = __hip_atomic_load(p + 0, __ATOMIC_RELAXED, __HIP_MEMORY_SCOPE_AGENT);
    v.y = __hip_atomic_load(p + 1, __ATOMIC_RELAXED, __HIP_MEMORY_SCOPE_AGENT);
    v.z = __hip_atomic_load(p + 2, __ATOMIC_RELAXED, __HIP_MEMORY_SCOPE_AGENT);
    v.w = __hip_atomic_load(p + 3, __ATOMIC_RELAXED, __HIP_MEMORY_SCOPE_AGENT);
    return v;
}

// x-projection (gi) for step snext of the given phase: partials + 32-lane
// butterfly; w==0 lanes write gi_buf[bq][g][c][i]. h-independent -> used to
// fill the barrier-wait window.
__device__ __forceinline__ void gi_compute(
    const float* __restrict__ emb, const int* __restrict__ src, const int* __restrict__ tgt,
    int phase, int snext, const float4* __restrict__ Ws4,
    float (*gi_buf)[3][4][4], int w, int bq, int b0)
{
    float acc[3][4][4];
    #pragma unroll
    for (int g = 0; g < 3; ++g)
        #pragma unroll
        for (int c = 0; c < 4; ++c)
            #pragma unroll
            for (int i = 0; i < 4; ++i) acc[g][c][i] = 0.f;
    float4 x0[4], x1[4];
    #pragma unroll
    for (int i = 0; i < 4; ++i) {
        int tk = phase ? (snext ? tgt[(snext - 1) * BB + b0 + i] : 1) : src[snext * BB + b0 + i];
        const float* xr = emb + (size_t)tk * EE + w * 4;
        x0[i] = *(const float4*)xr;
        x1[i] = *(const float4*)(xr + 128);
    }
    #pragma unroll
    for (int g = 0; g < 3; ++g)
        #pragma unroll
        for (int c = 0; c < 4; ++c) {
            float4 w0 = Ws4[(g * 4 + c) * 193 + w];
            float4 w1 = Ws4[(g * 4 + c) * 193 + w + 32];
            #pragma unroll
            for (int i = 0; i < 4; ++i)
                acc[g][c][i] += dot4(x0[i], w0) + dot4(x1[i], w1);
        }
    #pragma unroll
    for (int m = 1; m <= 16; m <<= 1)
        #pragma unroll
        for (int g = 0; g < 3; ++g)
            #pragma unroll
            for (int c = 0; c < 4; ++c)
                #pragma unroll
                for (int i = 0; i < 4; ++i)
                    acc[g][c][i] += __shfl_xor(acc[g][c][i], m);
    if (w == 0)
        #pragma unroll
        for (int g = 0; g < 3; ++g)
            #pragma unroll
            for (int c = 0; c < 4; ++c)
                *(float4*)&gi_buf[bq][g][c][0] =
                    make_float4(acc[g][c][0], acc[g][c][1], acc[g][c][2], acc[g][c][3]);
}

// ==================== persistent recurrence, distributed barrier ====================
// 128 blocks x 256 threads (coop for co-residency). Block owns 4 h-cols;
// W_ih+W_hh slice LDS-resident per phase. Barrier: 8 counter lines (one per
// blockIdx&7), wave0 parallel-poll; gi(t+1) computed in the wait window.
__global__ __launch_bounds__(256, 1) void k_rec3(
    const float* __restrict__ emb, const int* __restrict__ src, const int* __restrict__ tgt,
    const float* __restrict__ eWih, const float* __restrict__ eWhh,
    const float* __restrict__ ebih, const float* __restrict__ ebhh,
    const float* __restrict__ dWih, const float* __restrict__ dWhh,
    const float* __restrict__ dbih, const float* __restrict__ dbhh,
    float* __restrict__ hpp, float* __restrict__ Hall, int* __restrict__ arr)
{
    __shared__ float4 Ws4[12 * 193];
    __shared__ __align__(16) float gi_buf[8][3][4][4];   // [bq][g: r,z,nx][c][i]
    __shared__ __align__(16) float gh_buf[8][3][4][4];   // [bq][g: r,z,nh][c][i]
    const int tid = threadIdx.x;
    const int w   = tid & 31;
    const int bq  = tid >> 5;
    const int b0  = bq * 4;
    const int cg0 = blockIdx.x * 4;
    const int myline = (blockIdx.x & 7) * 64;

    int s = 0;   // global step 0..499
    for (int phase = 0; phase < 2; ++phase) {
        const float* Wih = phase ? dWih : eWih;
        const float* Whh = phase ? dWhh : eWhh;
        const float* bih = phase ? dbih : ebih;
        const float* bhh = phase ? dbhh : ebhh;

        for (int u = tid; u < 12 * 192; u += 256) {
            int r = u / 192, q = u - r * 192;
            int g = r >> 2, c = r & 3;
            size_t row = (size_t)(g * HH + cg0 + c);
            float4 v;
            if (q < 64) v = *(const float4*)(Wih + row * EE + q * 4);
            else        v = *(const float4*)(Whh + row * HH + (q - 64) * 4);
            Ws4[r * 193 + q] = v;
        }
        float br_ = 0.f, bz_ = 0.f, bnx_ = 0.f, bnh_ = 0.f;
        if (tid < 128) {
            int cg = cg0 + (tid & 3);
            br_  = bih[cg] + bhh[cg];
            bz_  = bih[HH + cg] + bhh[HH + cg];
            bnx_ = bih[2 * HH + cg];
            bnh_ = bhh[2 * HH + cg];
        }
        __syncthreads();

        // prologue: gi for first step of this phase
        gi_compute(emb, src, tgt, phase, 0, Ws4, gi_buf, w, bq, b0);
        __syncthreads();

        const int T = phase ? TT : SS;
        for (int t = 0; t < T; ++t, ++s) {
            const float* hprev; float* hnext;
            if (phase == 0) {
                hprev = hpp + (t & 1) * (BB * HH);
                hnext = hpp + ((t + 1) & 1) * (BB * HH);
            } else {
                hprev = t ? (Hall + (size_t)(t - 1) * (BB * HH)) : hpp;
                hnext = Hall + (size_t)t * (BB * HH);
            }

            // ---- gh = W_hh @ h_prev (critical path) ----
            float4 hf[4][4];
            #pragma unroll
            for (int i = 0; i < 4; ++i) {
                const float* hr = hprev + (b0 + i) * HH + w * 4;
                #pragma unroll
                for (int jh = 0; jh < 4; ++jh) hf[i][jh] = ld4_coh(hr + jh * 128);
            }
            float ah[3][4][4];
            #pragma unroll
            for (int g = 0; g < 3; ++g)
                #pragma unroll
                for (int c = 0; c < 4; ++c)
                    #pragma unroll
                    for (int i = 0; i < 4; ++i) ah[g][c][i] = 0.f;
            #pragma unroll
            for (int jh = 0; jh < 4; ++jh)
                #pragma unroll
                for (int g = 0; g < 3; ++g)
                    #pragma unroll
                    for (int c = 0; c < 4; ++c) {
                        float4 wv = Ws4[(g * 4 + c) * 193 + 64 + w + 32 * jh];
                        #pragma unroll
                        for (int i = 0; i < 4; ++i)
                            ah[g][c][i] += dot4(hf[i][jh], wv);
                    }
            #pragma unroll
            for (int m = 1; m <= 16; m <<= 1)
                #pragma unroll
                for (int g = 0; g < 3; ++g)
                    #pragma unroll
                    for (int c = 0; c < 4; ++c)
                        #pragma unroll
                        for (int i = 0; i < 4; ++i)
                            ah[g][c][i] += __shfl_xor(ah[g][c][i], m);
            if (w == 0)
                #pragma unroll
                for (int g = 0; g < 3; ++g)
                    #pragma unroll
                    for (int c = 0; c < 4; ++c)
                        *(float4*)&gh_buf[bq][g][c][0] =
                            make_float4(ah[g][c][0], ah[g][c][1], ah[g][c][2], ah[g][c][3]);
            __syncthreads();

            // ---- activation + coherent h store ----
            if (tid < 128) {
                int b = tid >> 2, c = tid & 3;
                int bq2 = b >> 2, i2 = b & 3;
                float gr  = gi_buf[bq2][0][c][i2] + gh_buf[bq2][0][c][i2] + br_;
                float gz  = gi_buf[bq2][1][c][i2] + gh_buf[bq2][1][c][i2] + bz_;
                float gnx = gi_buf[bq2][2][c][i2] + bnx_;
                float gnh = gh_buf[bq2][2][c][i2] + bnh_;
                float r = 1.f / (1.f + expf(-gr));
                float z = 1.f / (1.f + expf(-gz));
                float n = tanhf(gnx + r * gnh);
                float hp = __hip_atomic_load(hprev + b * HH + cg0 + c,
                                             __ATOMIC_RELAXED, __HIP_MEMORY_SCOPE_AGENT);
                __hip_atomic_store(hnext + b * HH + cg0 + c, (1.f - z) * n + z * hp,
                                   __ATOMIC_RELAXED, __HIP_MEMORY_SCOPE_AGENT);
            }
            __builtin_amdgcn_s_waitcnt(0);     // this wave's stores at the MALL
            __syncthreads();                   // => all waves' stores at the MALL

            // ---- arrive (distributed lines) ----
            if (tid == 0)
                __hip_atomic_fetch_add(arr + (size_t)s * 512 + myline, 1,
                                       __ATOMIC_RELAXED, __HIP_MEMORY_SCOPE_AGENT);

            // ---- overlap: gi for next step (h-independent) ----
            if (t < T - 1)
                gi_compute(emb, src, tgt, phase, t + 1, Ws4, gi_buf, w, bq, b0);

            // ---- wait: wave0 parallel-polls the 8 lines ----
            if (tid < 64) {
                const int* base = arr + (size_t)s * 512;
                for (;;) {
                    int v = 0;
                    if (tid < 8)
                        v = __hip_atomic_load(base + tid * 64,
                                              __ATOMIC_RELAXED, __HIP_MEMORY_SCOPE_AGENT);
                    v += __shfl_xor(v, 1);
                    v += __shfl_xor(v, 2);
                    v += __shfl_xor(v, 4);
                    if (__shfl(v, 0) == NBLK) break;
                    __builtin_amdgcn_s_sleep(1);
                }
            }
            __syncthreads();
        }
    }
}

// ==================== R1-proven fallback (per-step launches) ====================
__device__ __forceinline__ void gru_step_body(
    const float* __restrict__ emb, const int* __restrict__ tok, int sos,
    const float* __restrict__ Wih, const float* __restrict__ Whh,
    const float* __restrict__ bih, const float* __restrict__ bhh,
    const float* __restrict__ h_in, float* __restrict__ h_out,
    float (*z)[772], float (*part)[3][16][16],
    int tid, int cblk, int bg0)
{
    #pragma unroll
    for (int i = 0; i < 4; ++i) {
        int idx = tid + i * 768;
        if (idx < 1024) {
            int bl = idx >> 6, k4 = idx & 63;
            int tk = sos ? 1 : tok[bg0 + bl];
            *(float4*)&z[bl][k4 * 4] = *(const float4*)(emb + (size_t)tk * EE + k4 * 4);
        } else {
            int j = idx - 1024;
            int bl = j >> 7, k4 = j & 127;
            *(float4*)&z[bl][256 + k4 * 4] = *(const float4*)(h_in + (bg0 + bl) * HH + k4 * 4);
        }
    }
    __syncthreads();
    const int b  = tid & 15;
    const int c  = (tid >> 4) & 15;
    const int kp = tid >> 8;
    const int cg = cblk * 16 + c;
    const float *w0, *w1, *w2; int koff;
    if (kp == 0) {
        w0 = Wih + (size_t)(0 * HH + cg) * EE;
        w1 = Wih + (size_t)(1 * HH + cg) * EE;
        w2 = Wih + (size_t)(2 * HH + cg) * EE;
        koff = 0;
    } else {
        int o = (kp == 1) ? 0 : 256;
        w0 = Whh + (size_t)(0 * HH + cg) * HH + o;
        w1 = Whh + (size_t)(1 * HH + cg) * HH + o;
        w2 = Whh + (size_t)(2 * HH + cg) * HH + o;
        koff = 256 + o;
    }
    float a0 = 0.f, a1 = 0.f, a2 = 0.f;
    #pragma unroll 8
    for (int k4 = 0; k4 < 64; ++k4) {
        float4 zv = *(const float4*)&z[b][koff + k4 * 4];
        float4 v0 = *(const float4*)(w0 + k4 * 4);
        float4 v1 = *(const float4*)(w1 + k4 * 4);
        float4 v2 = *(const float4*)(w2 + k4 * 4);
        a0 += zv.x * v0.x + zv.y * v0.y + zv.z * v0.z + zv.w * v0.w;
        a1 += zv.x * v1.x + zv.y * v1.y + zv.z * v1.z + zv.w * v1.w;
        a2 += zv.x * v2.x + zv.y * v2.y + zv.z * v2.z + zv.w * v2.w;
    }
    part[kp][0][c][b] = a0;
    part[kp][1][c][b] = a1;
    part[kp][2][c][b] = a2;
    __syncthreads();
    if (kp == 0) {
        float gr  = part[0][0][c][b] + part[1][0][c][b] + part[2][0][c][b];
        float gz  = part[0][1][c][b] + part[1][1][c][b] + part[2][1][c][b];
        float gin = part[0][2][c][b];
        float ghn = part[1][2][c][b] + part[2][2][c][b];
        float r  = 1.f / (1.f + expf(-(gr + bih[cg] + bhh[cg])));
        float zg = 1.f / (1.f + expf(-(gz + bih[HH + cg] + bhh[HH + cg])));
        float n  = tanhf(gin + bih[2 * HH + cg] + r * (ghn + bhh[2 * HH + cg]));
        float hp = z[b][256 + cg];
        h_out[(bg0 + b) * HH + cg] = (1.f - zg) * n + zg * hp;
    }
}

__global__ __launch_bounds__(768) void k_gru(
    const float* __restrict__ emb, const int* __restrict__ tok, int sos,
    const float* __restrict__ Wih, const float* __restrict__ Whh,
    const float* __restrict__ bih, const float* __restrict__ bhh,
    const float* __restrict__ h_in, float* __restrict__ h_out)
{
    __shared__ float z[16][772];
    __shared__ float part[3][3][16][16];
    gru_step_body(emb, tok, sos, Wih, Whh, bih, bhh, h_in, h_out,
                  z, part, threadIdx.x, blockIdx.x & 31, (blockIdx.x >> 5) * 16);
}

// ==================== output path (unchanged) ====================
__global__ __launch_bounds__(256) void k_outemb(
    const float* __restrict__ Hall, const float* __restrict__ preW,
    const float* __restrict__ preb, float* __restrict__ OE)
{
    __shared__ float hs[16][516];
    const int tid = threadIdx.x;
    const int c0 = blockIdx.x * 64;
    const int r0 = blockIdx.y * 16;
    #pragma unroll
    for (int i = 0; i < 8; ++i) {
        int idx = tid + i * 256;
        int rr = idx >> 7, k4 = idx & 127;
        *(float4*)&hs[rr][k4 * 4] = *(const float4*)(Hall + (size_t)(r0 + rr) * HH + k4 * 4);
    }
    __syncthreads();
    const int rr = tid & 15, cc = tid >> 4;
    int cj[4]; float acc[4];
    #pragma unroll
    for (int j = 0; j < 4; ++j) { cj[j] = c0 + cc + 16 * j; acc[j] = preb[cj[j]]; }
    for (int k4 = 0; k4 < 128; ++k4) {
        float4 hv = *(const float4*)&hs[rr][k4 * 4];
        #pragma unroll
        for (int j = 0; j < 4; ++j) {
            float4 wv = *(const float4*)(preW + (size_t)cj[j] * HH + k4 * 4);
            acc[j] += hv.x * wv.x + hv.y * wv.y + hv.z * wv.z + hv.w * wv.w;
        }
    }
    #pragma unroll
    for (int j = 0; j < 4; ++j) OE[(size_t)(r0 + rr) * EE + cj[j]] = acc[j];
}

__global__ __launch_bounds__(128) void k_logits(
    const float* __restrict__ OE, const float* __restrict__ emb,
    const float* __restrict__ outb, const int* __restrict__ tgt,
    float* __restrict__ m_arr, float* __restrict__ z_arr,
    unsigned int* __restrict__ am_arr, float* __restrict__ gold_arr)
{
    __shared__ float oes[32][260];
    __shared__ float ems[256][18];
    const int tid = threadIdx.x;
    const int c0 = blockIdx.x * 256;
    const int r0 = blockIdx.y * 32;

    #pragma unroll
    for (int i = 0; i < 16; ++i) {
        int idx = tid + i * 128;
        int rr2 = idx >> 6, k4 = idx & 63;
        *(float4*)&oes[rr2][k4 * 4] = *(const float4*)(OE + (size_t)(r0 + rr2) * EE + k4 * 4);
    }

    const int rr  = tid >> 5;
    const int ccg = tid & 31;
    float acc[8][8];
    #pragma unroll
    for (int i = 0; i < 8; ++i)
        #pragma unroll
        for (int j = 0; j < 8; ++j) acc[i][j] = 0.f;

    for (int kc = 0; kc < 16; ++kc) {
        __syncthreads();
        #pragma unroll
        for (int i = 0; i < 16; ++i) {
            int idx = tid + i * 128;
            int col = idx >> 3, f2 = idx & 7;
            *(float2*)&ems[col][f2 * 2] =
                *(const float2*)(emb + (size_t)(c0 + col) * EE + kc * 16 + f2 * 2);
        }
        __syncthreads();
        #pragma unroll
        for (int kk = 0; kk < 16; kk += 4) {
            float4 ov[8];
            #pragma unroll
            for (int i = 0; i < 8; ++i) ov[i] = *(const float4*)&oes[rr * 8 + i][kc * 16 + kk];
            #pragma unroll
            for (int j = 0; j < 8; ++j) {
                float2 e0 = *(const float2*)&ems[ccg + 32 * j][kk];
                float2 e1 = *(const float2*)&ems[ccg + 32 * j][kk + 2];
                #pragma unroll
                for (int i = 0; i < 8; ++i)
                    acc[i][j] += ov[i].x * e0.x + ov[i].y * e0.y + ov[i].z * e1.x + ov[i].w * e1.y;
            }
        }
    }

    #pragma unroll
    for (int i = 0; i < 8; ++i) {
        int r = r0 + rr * 8 + i;
        int gold = tgt[r];
        float vals[8]; float m = -3.4e38f; int cb = 0x7fffffff;
        #pragma unroll
        for (int j = 0; j < 8; ++j) {
            int cj = c0 + ccg + 32 * j;
            float v = acc[i][j] + outb[cj];
            vals[j] = v;
            if (v > m) { m = v; cb = cj; }
            if (cj == gold) gold_arr[r] = v;
        }
        for (int mk = 1; mk <= 16; mk <<= 1) {
            float mo = __shfl_xor(m, mk);
            int   co = __shfl_xor(cb, mk);
            if (mo > m || (mo == m && co < cb)) { m = mo; cb = co; }
        }
        float s = 0.f;
        #pragma unroll
        for (int j = 0; j < 8; ++j) s += expf(vals[j] - m);
        for (int mk = 1; mk <= 16; mk <<= 1) s += __shfl_xor(s, mk);
        if (ccg == 0) {
            size_t p = (size_t)blockIdx.x * 3200 + r;
            m_arr[p] = m; z_arr[p] = s; am_arr[p] = (unsigned)cb;
        }
    }
}

__global__ __launch_bounds__(256) void k_merge(
    const float* __restrict__ m_arr, const float* __restrict__ z_arr,
    const unsigned* __restrict__ am_arr, const float* __restrict__ gold_arr,
    float* __restrict__ nll, float* __restrict__ out)
{
    int r = blockIdx.x * 256 + threadIdx.x;
    if (r >= 3200) return;
    float M = -3.4e38f, Z = 0.f, bm = -3.4e38f; unsigned bc = 0u;
    for (int s = 0; s < 125; ++s) {
        size_t p = (size_t)s * 3200 + r;
        float ms = m_arr[p]; float zs = z_arr[p]; unsigned cs = am_arr[p];
        if (ms > M) { Z = Z * expf(M - ms) + zs; M = ms; }
        else        { Z += zs * expf(ms - M); }
        if (ms > bm || (ms == bm && cs < bc)) { bm = ms; bc = cs; }
    }
    float pg = expf(gold_arr[r] - M) / Z;
    nll[r] = -logf(pg + 1e-20f);
    out[r] = (float)bc;
}

__global__ __launch_bounds__(128) void k_loss(
    const float* __restrict__ nll, const int* __restrict__ tgt, float* __restrict__ out)
{
    __shared__ float ls[128];
    int t = threadIdx.x;
    float lt = 0.f;
    if (t < TT) {
        float s = 0.f; int cnt = 0;
        for (int b = 0; b < BB; ++b) {
            int g = tgt[t * BB + b];
            if (g != 0) { s += nll[t * BB + b]; cnt++; }
        }
        lt = s / fmaxf((float)cnt, 1.f);
    }
    ls[t] = lt;
    __syncthreads();
    for (int off = 64; off > 0; off >>= 1) {
        if (t < off) ls[t] += ls[t + off];
        __syncthreads();
    }
    if (t == 0) out[3200] = ls[0];
}

extern "C" void kernel_launch(void* const* d_in, const int* in_sizes, int n_in,
                              void* d_out, int out_size, void* d_ws, size_t ws_size,
                              hipStream_t stream) {
    const int*   src  = (const int*)  d_in[0];
    const int*   tgt  = (const int*)  d_in[1];
    const float* emb  = (const float*)d_in[2];
    const float* eWih = (const float*)d_in[3];
    const float* eWhh = (const float*)d_in[4];
    const float* ebih = (const float*)d_in[5];
    const float* ebhh = (const float*)d_in[6];
    const float* dWih = (const float*)d_in[7];
    const float* dWhh = (const float*)d_in[8];
    const float* dbih = (const float*)d_in[9];
    const float* dbhh = (const float*)d_in[10];
    const float* preW = (const float*)d_in[11];
    const float* preb = (const float*)d_in[12];
    const float* outb = (const float*)d_in[13];

    float* ws   = (float*)d_ws;
    float* out  = (float*)d_out;
    float* hpp  = ws + WS_HPP;
    int*   arr  = (int*)(ws + WS_ARR);
    float* Hall = ws + WS_HALL;
    float* OE   = ws + WS_OE;
    float* m_a  = ws + WS_M;
    float* z_a  = ws + WS_ZZ;
    unsigned* am_a = (unsigned*)(ws + WS_AM);
    float* gold = ws + WS_GOLD;
    float* nll  = ws + WS_NLL;

    // zero h0 + all barrier counter lines (ws re-poisoned before every call)
    k_zero<<<1128, 256, 0, stream>>>(ws, 288768);

    hipError_t coop_err;
    {
        const float* emb_ = emb; const int* src_ = src; const int* tgt_ = tgt;
        const float* a3 = eWih; const float* a4 = eWhh; const float* a5 = ebih; const float* a6 = ebhh;
        const float* a7 = dWih; const float* a8 = dWhh; const float* a9 = dbih; const float* a10 = dbhh;
        float* hpp_ = hpp; float* Hall_ = Hall; int* arr_ = arr;
        void* args[] = { (void*)&emb_, (void*)&src_, (void*)&tgt_,
                         (void*)&a3, (void*)&a4, (void*)&a5, (void*)&a6,
                         (void*)&a7, (void*)&a8, (void*)&a9, (void*)&a10,
                         (void*)&hpp_, (void*)&Hall_, (void*)&arr_ };
        coop_err = hipLaunchCooperativeKernel((const void*)k_rec3, dim3(NBLK), dim3(256),
                                              args, 0, stream);
    }
    if (coop_err != hipSuccess) {
        for (int t = 0; t < SS; ++t) {
            const float* hin = hpp + (t & 1) * (BB * HH);
            float* hout      = hpp + ((t + 1) & 1) * (BB * HH);
            k_gru<<<64, 768, 0, stream>>>(emb, src + t * BB, 0,
                                          eWih, eWhh, ebih, ebhh, hin, hout);
        }
        for (int t = 0; t < TT; ++t) {
            const float* hin = (t == 0) ? hpp : (Hall + (size_t)(t - 1) * BB * HH);
            float* hout      = Hall + (size_t)t * BB * HH;
            const int* tp    = (t == 0) ? src : (tgt + (t - 1) * BB);
            k_gru<<<64, 768, 0, stream>>>(emb, tp, (t == 0) ? 1 : 0,
                                          dWih, dWhh, dbih, dbhh, hin, hout);
        }
    }

    k_outemb<<<dim3(4, 200), 256, 0, stream>>>(Hall, preW, preb, OE);
    k_logits<<<dim3(125, 100), 128, 0, stream>>>(OE, emb, outb, tgt, m_a, z_a, am_a, gold);
    k_merge<<<13, 256, 0, stream>>>(m_a, z_a, am_a, gold, nll, out);
    k_loss<<<1, 128, 0, stream>>>(nll, tgt, out);
}